// Round 3
// baseline (775.244 us; speedup 1.0000x reference)
//
#include <hip/hip_runtime.h>
#include <hip/hip_bf16.h>

#define DIN 256
#define DH  1024
#define DF  512
#define NROWS 65536

// workspace layout (bytes)
#define WS_WTS   0
#define WS_PB    4718592
#define WS_PC    4980736
#define WS_CNT   5242880
#define WS_OFFS  5243904

typedef __attribute__((ext_vector_type(8))) short bf16x8;
typedef __attribute__((ext_vector_type(4))) float f32x4;

__device__ __forceinline__ unsigned short f2b(float f) {
    union { float f; unsigned u; } v; v.f = f;
    unsigned r = v.u + 0x7FFFu + ((v.u >> 16) & 1u);
    return (unsigned short)(r >> 16);
}

__device__ __forceinline__ void gll16(const void* g, void* l) {
    __builtin_amdgcn_global_load_lds(
        (const __attribute__((address_space(1))) void*)g,
        (__attribute__((address_space(3))) void*)l, 16, 0, 0);
}

// raw barriers with counted vmcnt (T3/T4): never drain in-flight prefetches
#define WAIT_TOP() asm volatile("s_waitcnt vmcnt(8) lgkmcnt(0)\ns_barrier" ::: "memory")
#define WAIT_MID() asm volatile("s_waitcnt vmcnt(4) lgkmcnt(0)\ns_barrier" ::: "memory")
#define WAIT_LGKM() asm volatile("s_waitcnt lgkmcnt(0)\ns_barrier" ::: "memory")

// dst[n][k] = (bf16) src[k][n] ; src is K x N row-major fp32
__global__ __launch_bounds__(256) void transpose_to_bf16(
        const float* __restrict__ src, unsigned short* __restrict__ dst,
        int K, int N) {
    __shared__ float tile[64][65];
    int k0 = blockIdx.x * 64, n0 = blockIdx.y * 64;
    int t = threadIdx.x;
    for (int i = 0; i < 16; ++i) {
        int idx = t + i * 256;
        int kk = idx >> 6, nn = idx & 63;
        tile[kk][nn] = src[(size_t)(k0 + kk) * N + (n0 + nn)];
    }
    __syncthreads();
    for (int i = 0; i < 16; ++i) {
        int idx = t + i * 256;
        int nn = idx >> 6, kk = idx & 63;
        dst[(size_t)(n0 + nn) * K + (k0 + kk)] = f2b(tile[kk][nn]);
    }
}

__device__ __forceinline__ int row_tag(const float* obs, int row) {
    float c2 = obs[(size_t)row * DIN + 2];
    float c3 = obs[(size_t)row * DIN + 3];
    return (c2 == 1.0f && c3 == 0.0f) ? 1 : 0;
}

__global__ __launch_bounds__(256) void tag_count(const float* __restrict__ obs,
                                                 int* __restrict__ cnt) {
    int t = threadIdx.x;
    int tag = row_tag(obs, blockIdx.x * 256 + t);
    unsigned long long m = __ballot(tag);
    __shared__ int wc[4];
    if ((t & 63) == 0) wc[t >> 6] = __popcll(m);
    __syncthreads();
    if (t == 0) cnt[blockIdx.x] = wc[0] + wc[1] + wc[2] + wc[3];
}

__global__ __launch_bounds__(256) void scan256(const int* __restrict__ cnt,
                                               int* __restrict__ offs) {
    __shared__ int s[256];
    int t = threadIdx.x;
    s[t] = cnt[t];
    __syncthreads();
    for (int d = 1; d < 256; d <<= 1) {
        int v = (t >= d) ? s[t - d] : 0;
        __syncthreads();
        s[t] += v;
        __syncthreads();
    }
    offs[t] = s[t] - cnt[t];
    if (t == 255) offs[256] = s[255];
}

__global__ __launch_bounds__(256) void fill_perm(const float* __restrict__ obs,
                                                 const int* __restrict__ offs,
                                                 int* __restrict__ pb,
                                                 int* __restrict__ pc) {
    int t = threadIdx.x, bid = blockIdx.x;
    int row = bid * 256 + t;
    int tag = row_tag(obs, row);
    unsigned long long m = __ballot(tag);
    __shared__ int wc[4];
    int lane = t & 63, wv = t >> 6;
    if (lane == 0) wc[wv] = __popcll(m);
    __syncthreads();
    int woff = 0;
    for (int i = 0; i < 4; ++i) if (i < wv) woff += wc[i];
    int lb = woff + __popcll(m & ((1ull << lane) - 1ull));
    int base_b = offs[bid];
    if (tag) pb[base_b + lb] = row;
    else     pc[bid * 256 - base_b + (t - lb)] = row;
}

// LDS map (dynamic, 154112 B total, 1 block/CU):
//   [0, 64K)      : X transient [128][256] bf16 (prologue only), then:
//       ldsW2A @ 0      [256][64] bf16 = 32K   (W2 half 0, per chunk)
//       ldsW2B @ 32768  [256][64] bf16 = 32K   (W2 half 1)
//   ldsW1a @ 65536  [64][256] bf16 = 32K  (W1 chunk ping)
//   ldsW1b @ 98304  [64][256] bf16 = 32K  (W1 chunk pong)
//   ldsH   @ 131072 [128][64] bf16 = 16K
//   ldsB1  @ 147456 float[1024]
//   ldsB2  @ 151552 float[512]
//   ldsPr  @ 153600 int[128]
__global__ __launch_bounds__(512, 2) void fused_mlp(
    const float* __restrict__ obs,
    const unsigned short* __restrict__ wts,
    const int* __restrict__ perm_b, const int* __restrict__ perm_c,
    const int* __restrict__ offs,
    const float* __restrict__ b1_0, const float* __restrict__ b2_0,
    const float* __restrict__ b1_1, const float* __restrict__ b2_1,
    const float* __restrict__ b1_2, const float* __restrict__ b2_2,
    float* __restrict__ out)
{
    extern __shared__ char lds[];
    char* ldsW2A = lds;
    char* ldsW2B = lds + 32768;
    char* ldsW1a = lds + 65536;
    char* ldsW1b = lds + 98304;
    char* ldsH   = lds + 131072;
    float* ldsB1 = (float*)(lds + 147456);
    float* ldsB2 = (float*)(lds + 151552);
    int*  ldsPr  = (int*)(lds + 153600);

    const int bid = blockIdx.x;
    int branch, base, cnt;
    const int* perm;
    if (bid < 512) {
        branch = 2; base = bid * 128; cnt = NROWS; perm = nullptr;
    } else {
        int eb = bid - 512;
        int nb = offs[256];
        int nbb = (nb + 127) >> 7;
        int nc = NROWS - nb;
        int ncb = (nc + 127) >> 7;
        if (eb < nbb)            { branch = 0; base = eb * 128;         cnt = nb; perm = perm_b; }
        else if (eb < nbb + ncb) { branch = 1; base = (eb - nbb) * 128; cnt = nc; perm = perm_c; }
        else return;
    }

    const float* b1 = branch == 0 ? b1_0 : (branch == 1 ? b1_1 : b1_2);
    const float* b2 = branch == 0 ? b2_0 : (branch == 1 ? b2_1 : b2_2);
    const char* w1t = (const char*)(wts + (size_t)branch * (DH * DIN));
    const char* w2t = (const char*)(wts + (size_t)3 * DH * DIN + (size_t)branch * (DF * DH));

    const int t = threadIdx.x;
    const int lane = t & 63;
    const int w = t >> 6;
    const int l15 = lane & 15;
    const int g = lane >> 4;

    // ---- prologue: bias / perm-row tables into LDS (keeps the main loop's
    //      VMEM stream = exactly the 12 gll16s, so vmcnt counts are exact)
    ldsB1[t] = b1[t];
    ldsB1[t + 512] = b1[t + 512];
    ldsB2[t] = b2[t];
    if (t < 128) {
        int gr = base + t;
        ldsPr[t] = (gr < cnt) ? (perm ? perm[gr] : gr) : -1;
    }
    // ---- stage X [128][256] fp32->bf16, swizzled, into transient region
    #pragma unroll
    for (int i = 0; i < 16; ++i) {
        int idx = t + i * 512;            // 8192 float4 slots
        int r = idx >> 6, c4 = idx & 63;
        int gr = base + r;
        int grow = gr < cnt ? gr : cnt - 1;
        if (perm) grow = perm[grow];
        f32x4 v = *(const f32x4*)(obs + (size_t)grow * DIN + c4 * 4);
        ushort4 p4;
        p4.x = f2b(v.x); p4.y = f2b(v.y); p4.z = f2b(v.z); p4.w = f2b(v.w);
        *(ushort4*)(lds + r * 512 + ((c4 * 8) ^ ((r & 7) << 4))) = p4;
    }
    WAIT_LGKM();

    // ---- load persistent X A-frags (64 VGPR): wave rows rg*32..+32
    const int rg = w & 3, cg = w >> 2;   // GEMM1: 4 row-groups x 2 hcol-groups
    bf16x8 xf[2][8];
    #pragma unroll
    for (int art = 0; art < 2; ++art)
        #pragma unroll
        for (int kk = 0; kk < 8; ++kk) {
            int ar = rg * 32 + art * 16 + l15;
            xf[art][kk] = *(const bf16x8*)(lds + ar * 512 + ((kk * 64 + g * 16) ^ ((ar & 7) << 4)));
        }
    WAIT_LGKM();   // X region now dead -> becomes W2A/W2B

    // ---- issue chunk-0 prefetches: W1 first (4), then W2 halves (8)
    {
        #pragma unroll
        for (int i = 0; i < 4; ++i) {
            int slot = t + i * 512;
            int nl = slot >> 5, boff = (slot & 31) << 4;
            gll16(w1t + (size_t)(0 * 64 + nl) * 512 + (boff ^ ((nl & 7) << 4)),
                  ldsW1a + slot * 16);
        }
        #pragma unroll
        for (int h = 0; h < 2; ++h) {
            char* dst = h ? ldsW2B : ldsW2A;
            #pragma unroll
            for (int i = 0; i < 4; ++i) {
                int slot = t + i * 512;
                int nl = slot >> 3, boff = (slot & 7) << 4;
                gll16(w2t + (size_t)(h * 256 + nl) * 2048 + 0 * 128 + (boff ^ ((nl & 7) << 4)),
                      dst + slot * 16);
            }
        }
    }

    const int wr = w >> 2, wc = w & 3;   // GEMM2: 2 row-groups x 4 fcol-groups
    f32x4 accA[4][4], accB[4][4];
    #pragma unroll
    for (int a = 0; a < 4; ++a)
        #pragma unroll
        for (int b = 0; b < 4; ++b)
            #pragma unroll
            for (int e = 0; e < 4; ++e) { accA[a][b][e] = 0.0f; accB[a][b][e] = 0.0f; }

    for (int hc = 0; hc < 16; ++hc) {
        WAIT_TOP();   // retires W1[hc] (oldest 4); W2[hc] (8) stays in flight
        const char* W1cur = (hc & 1) ? ldsW1b : ldsW1a;

        // ---- GEMM1: H chunk [128][64], K=256, wave tile 32x32, A from regs
        f32x4 aH[2][2];
        #pragma unroll
        for (int a = 0; a < 2; ++a)
            #pragma unroll
            for (int b = 0; b < 2; ++b)
                #pragma unroll
                for (int e = 0; e < 4; ++e) aH[a][b][e] = 0.0f;
        const int nl0 = cg * 32 + l15;
        const int nl1 = nl0 + 16;
        const int sw0 = (nl0 & 7) << 4, sw1 = (nl1 & 7) << 4;
        __builtin_amdgcn_s_setprio(1);
        #pragma unroll
        for (int kk = 0; kk < 8; ++kk) {
            int kb = kk * 64 + g * 16;
            bf16x8 bb0 = *(const bf16x8*)(W1cur + nl0 * 512 + (kb ^ sw0));
            bf16x8 bb1 = *(const bf16x8*)(W1cur + nl1 * 512 + (kb ^ sw1));
            aH[0][0] = __builtin_amdgcn_mfma_f32_16x16x32_bf16(xf[0][kk], bb0, aH[0][0], 0, 0, 0);
            aH[0][1] = __builtin_amdgcn_mfma_f32_16x16x32_bf16(xf[0][kk], bb1, aH[0][1], 0, 0, 0);
            aH[1][0] = __builtin_amdgcn_mfma_f32_16x16x32_bf16(xf[1][kk], bb0, aH[1][0], 0, 0, 0);
            aH[1][1] = __builtin_amdgcn_mfma_f32_16x16x32_bf16(xf[1][kk], bb1, aH[1][1], 0, 0, 0);
        }
        __builtin_amdgcn_s_setprio(0);

        // ---- bias + relu -> ldsH  (D: col=l15 -> hcol, row=g*4+r -> batch row)
        {
            float b1v0 = ldsB1[hc * 64 + cg * 32 + l15];
            float b1v1 = ldsB1[hc * 64 + cg * 32 + 16 + l15];
            #pragma unroll
            for (int art = 0; art < 2; ++art)
                #pragma unroll
                for (int bct = 0; bct < 2; ++bct) {
                    int col2 = (cg * 32 + bct * 16 + l15) * 2;
                    float bv = bct ? b1v1 : b1v0;
                    #pragma unroll
                    for (int r = 0; r < 4; ++r) {
                        int hrow = rg * 32 + art * 16 + g * 4 + r;
                        float vv = fmaxf(aH[art][bct][r] + bv, 0.0f);
                        *(unsigned short*)(ldsH + hrow * 128 + (col2 ^ ((hrow & 7) << 4))) = f2b(vv);
                    }
                }
        }

        // ---- issue W1[hc+1] into the other ping-pong buffer (hides under GEMM2)
        {
            char* dst = (hc & 1) ? ldsW1a : ldsW1b;
            int nchunk = (hc + 1) & 15;
            #pragma unroll
            for (int i = 0; i < 4; ++i) {
                int slot = t + i * 512;
                int nl = slot >> 5, boff = (slot & 31) << 4;
                gll16(w1t + (size_t)(nchunk * 64 + nl) * 512 + (boff ^ ((nl & 7) << 4)),
                      dst + slot * 16);
            }
        }

        WAIT_MID();   // retires W2[hc] (oldest 8); W1[hc+1] (4) stays in flight

        // ---- GEMM2 A-frags from H (reused across both halves)
        bf16x8 hA[4][2];
        #pragma unroll
        for (int rt = 0; rt < 4; ++rt)
            #pragma unroll
            for (int k2 = 0; k2 < 2; ++k2) {
                int hr = wr * 64 + rt * 16 + l15;
                hA[rt][k2] = *(const bf16x8*)(ldsH + hr * 128 + ((k2 * 64 + g * 16) ^ ((hr & 7) << 4)));
            }

        // ---- GEMM2: out[128][512] partial (k=64), wave tile 64x64 per half
        const int fc = wc * 64 + l15;   // +ct*16
        const int fsw0 = ((fc) & 7) << 4;
        __builtin_amdgcn_s_setprio(1);
        #pragma unroll
        for (int k2 = 0; k2 < 2; ++k2)
            #pragma unroll
            for (int ct = 0; ct < 4; ++ct) {
                int fr = fc + ct * 16;
                bf16x8 bb = *(const bf16x8*)(ldsW2A + fr * 128 + ((k2 * 64 + g * 16) ^ fsw0));
                #pragma unroll
                for (int rt = 0; rt < 4; ++rt)
                    accA[rt][ct] = __builtin_amdgcn_mfma_f32_16x16x32_bf16(hA[rt][k2], bb, accA[rt][ct], 0, 0, 0);
            }
        #pragma unroll
        for (int k2 = 0; k2 < 2; ++k2)
            #pragma unroll
            for (int ct = 0; ct < 4; ++ct) {
                int fr = fc + ct * 16;
                bf16x8 bb = *(const bf16x8*)(ldsW2B + fr * 128 + ((k2 * 64 + g * 16) ^ fsw0));
                #pragma unroll
                for (int rt = 0; rt < 4; ++rt)
                    accB[rt][ct] = __builtin_amdgcn_mfma_f32_16x16x32_bf16(hA[rt][k2], bb, accB[rt][ct], 0, 0, 0);
            }
        __builtin_amdgcn_s_setprio(0);

        WAIT_LGKM();  // all W2 reads done; W1[hc+1] still in flight

        // ---- issue W2[hc+1] halves (hide under next chunk's GEMM1)
        {
            int nchunk = (hc + 1) & 15;
            #pragma unroll
            for (int h = 0; h < 2; ++h) {
                char* dst = h ? ldsW2B : ldsW2A;
                #pragma unroll
                for (int i = 0; i < 4; ++i) {
                    int slot = t + i * 512;
                    int nl = slot >> 3, boff = (slot & 7) << 4;
                    gll16(w2t + (size_t)(h * 256 + nl) * 2048 + nchunk * 128 + (boff ^ ((nl & 7) << 4)),
                          dst + slot * 16);
                }
            }
        }
    }

    // ---- epilogue: bias2 + permuted scatter store
    int colq[8]; float b2v[8];
    #pragma unroll
    for (int q = 0; q < 8; ++q) {
        colq[q] = (q >> 2) * 256 + wc * 64 + (q & 3) * 16 + l15;
        b2v[q] = ldsB2[colq[q]];
    }
    const int cb = (branch == 2) ? DF : 0;
    #pragma unroll
    for (int rt = 0; rt < 4; ++rt)
        #pragma unroll
        for (int r = 0; r < 4; ++r) {
            int row = wr * 64 + rt * 16 + g * 4 + r;
            int prow = ldsPr[row];
            if (prow >= 0) {
                float* op = out + (size_t)prow * (2 * DF) + cb;
                op[colq[0]] = accA[rt][0][r] + b2v[0];
                op[colq[1]] = accA[rt][1][r] + b2v[1];
                op[colq[2]] = accA[rt][2][r] + b2v[2];
                op[colq[3]] = accA[rt][3][r] + b2v[3];
                op[colq[4]] = accB[rt][0][r] + b2v[4];
                op[colq[5]] = accB[rt][1][r] + b2v[5];
                op[colq[6]] = accB[rt][2][r] + b2v[6];
                op[colq[7]] = accB[rt][3][r] + b2v[7];
            }
        }
}

extern "C" void kernel_launch(void* const* d_in, const int* in_sizes, int n_in,
                              void* d_out, int out_size, void* d_ws, size_t ws_size,
                              hipStream_t stream) {
    const float* obs = (const float*)d_in[0];
    const float* W1[3] = {(const float*)d_in[1], (const float*)d_in[5], (const float*)d_in[9]};
    const float* b1[3] = {(const float*)d_in[2], (const float*)d_in[6], (const float*)d_in[10]};
    const float* W2[3] = {(const float*)d_in[3], (const float*)d_in[7], (const float*)d_in[11]};
    const float* b2[3] = {(const float*)d_in[4], (const float*)d_in[8], (const float*)d_in[12]};

    char* ws = (char*)d_ws;
    unsigned short* wts = (unsigned short*)(ws + WS_WTS);
    int* pb   = (int*)(ws + WS_PB);
    int* pc   = (int*)(ws + WS_PC);
    int* cnt  = (int*)(ws + WS_CNT);
    int* offs = (int*)(ws + WS_OFFS);

    for (int br = 0; br < 3; ++br) {
        transpose_to_bf16<<<dim3(DIN / 64, DH / 64), 256, 0, stream>>>(
            W1[br], wts + (size_t)br * DH * DIN, DIN, DH);
        transpose_to_bf16<<<dim3(DH / 64, DF / 64), 256, 0, stream>>>(
            W2[br], wts + (size_t)3 * DH * DIN + (size_t)br * DF * DH, DH, DF);
    }
    tag_count<<<256, 256, 0, stream>>>(obs, cnt);
    scan256<<<1, 256, 0, stream>>>(cnt, offs);
    fill_perm<<<256, 256, 0, stream>>>(obs, offs, pb, pc);

    hipFuncSetAttribute((const void*)fused_mlp,
                        hipFuncAttributeMaxDynamicSharedMemorySize, 154112);
    fused_mlp<<<1025, 512, 154112, stream>>>(obs, wts, pb, pc, offs,
        b1[0], b2[0], b1[1], b2[1], b1[2], b2[2], (float*)d_out);
}

// Round 5
// 752.650 us; speedup vs baseline: 1.0300x; 1.0300x over previous
//
#include <hip/hip_runtime.h>
#include <hip/hip_bf16.h>

#define DIN 256
#define DH  1024
#define DF  512
#define NROWS 65536

// workspace layout (bytes)
#define WS_WTS   0
#define WS_PB    4718592
#define WS_PC    4980736
#define WS_CNT   5242880
#define WS_OFFS  5243904

typedef __attribute__((ext_vector_type(8))) short bf16x8;
typedef __attribute__((ext_vector_type(4))) float f32x4;

__device__ __forceinline__ unsigned short f2b(float f) {
    union { float f; unsigned u; } v; v.f = f;
    unsigned r = v.u + 0x7FFFu + ((v.u >> 16) & 1u);
    return (unsigned short)(r >> 16);
}

__device__ __forceinline__ void gll16(const void* g, void* l) {
    __builtin_amdgcn_global_load_lds(
        (const __attribute__((address_space(1))) void*)g,
        (__attribute__((address_space(3))) void*)l, 16, 0, 0);
}

// raw barriers with counted vmcnt (T3/T4) — EXACT R3 structure (validated to run)
#define WAIT_TOP() asm volatile("s_waitcnt vmcnt(8) lgkmcnt(0)\ns_barrier" ::: "memory")
#define WAIT_MID() asm volatile("s_waitcnt vmcnt(4) lgkmcnt(0)\ns_barrier" ::: "memory")
#define WAIT_LGKM() asm volatile("s_waitcnt lgkmcnt(0)\ns_barrier" ::: "memory")

// dst[n][k] = (bf16) src[k][n] ; src is K x N row-major fp32
__global__ __launch_bounds__(256) void transpose_to_bf16(
        const float* __restrict__ src, unsigned short* __restrict__ dst,
        int K, int N) {
    __shared__ float tile[64][65];
    int k0 = blockIdx.x * 64, n0 = blockIdx.y * 64;
    int t = threadIdx.x;
    for (int i = 0; i < 16; ++i) {
        int idx = t + i * 256;
        int kk = idx >> 6, nn = idx & 63;
        tile[kk][nn] = src[(size_t)(k0 + kk) * N + (n0 + nn)];
    }
    __syncthreads();
    for (int i = 0; i < 16; ++i) {
        int idx = t + i * 256;
        int nn = idx >> 6, kk = idx & 63;
        dst[(size_t)(n0 + nn) * K + (k0 + kk)] = f2b(tile[kk][nn]);
    }
}

__device__ __forceinline__ int row_tag(const float* obs, int row) {
    float c2 = obs[(size_t)row * DIN + 2];
    float c3 = obs[(size_t)row * DIN + 3];
    return (c2 == 1.0f && c3 == 0.0f) ? 1 : 0;
}

__global__ __launch_bounds__(256) void tag_count(const float* __restrict__ obs,
                                                 int* __restrict__ cnt) {
    int t = threadIdx.x;
    int tag = row_tag(obs, blockIdx.x * 256 + t);
    unsigned long long m = __ballot(tag);
    __shared__ int wc[4];
    if ((t & 63) == 0) wc[t >> 6] = __popcll(m);
    __syncthreads();
    if (t == 0) cnt[blockIdx.x] = wc[0] + wc[1] + wc[2] + wc[3];
}

__global__ __launch_bounds__(256) void scan256(const int* __restrict__ cnt,
                                               int* __restrict__ offs) {
    __shared__ int s[256];
    int t = threadIdx.x;
    s[t] = cnt[t];
    __syncthreads();
    for (int d = 1; d < 256; d <<= 1) {
        int v = (t >= d) ? s[t - d] : 0;
        __syncthreads();
        s[t] += v;
        __syncthreads();
    }
    offs[t] = s[t] - cnt[t];
    if (t == 255) offs[256] = s[255];
}

__global__ __launch_bounds__(256) void fill_perm(const float* __restrict__ obs,
                                                 const int* __restrict__ offs,
                                                 int* __restrict__ pb,
                                                 int* __restrict__ pc) {
    int t = threadIdx.x, bid = blockIdx.x;
    int row = bid * 256 + t;
    int tag = row_tag(obs, row);
    unsigned long long m = __ballot(tag);
    __shared__ int wc[4];
    int lane = t & 63, wv = t >> 6;
    if (lane == 0) wc[wv] = __popcll(m);
    __syncthreads();
    int woff = 0;
    for (int i = 0; i < 4; ++i) if (i < wv) woff += wc[i];
    int lb = woff + __popcll(m & ((1ull << lane) - 1ull));
    int base_b = offs[bid];
    if (tag) pb[base_b + lb] = row;
    else     pc[bid * 256 - base_b + (t - lb)] = row;
}

// LDS map (dynamic, 154112 B total, 1 block/CU):
//   [0, 64K)      : X transient [128][256] bf16 (prologue only), then:
//       ldsW2A @ 0      [256][64] bf16 = 32K   (W2 half 0, per chunk)
//       ldsW2B @ 32768  [256][64] bf16 = 32K   (W2 half 1)
//   ldsW1a @ 65536  [64][256] bf16 = 32K  (W1 chunk ping)
//   ldsW1b @ 98304  [64][256] bf16 = 32K  (W1 chunk pong)
//   ldsH   @ 131072 [128][64] bf16 = 16K
//   ldsB1  @ 147456 float[1024]
//   ldsB2  @ 151552 float[512]
//   ldsPr  @ 153600 int[128]
__global__ __launch_bounds__(512, 2) void fused_mlp(
    const float* __restrict__ obs,
    const unsigned short* __restrict__ wts,
    const int* __restrict__ perm_b, const int* __restrict__ perm_c,
    const int* __restrict__ offs,
    const float* __restrict__ b1_0, const float* __restrict__ b2_0,
    const float* __restrict__ b1_1, const float* __restrict__ b2_1,
    const float* __restrict__ b1_2, const float* __restrict__ b2_2,
    float* __restrict__ out)
{
    extern __shared__ char lds[];
    char* ldsW2A = lds;
    char* ldsW2B = lds + 32768;
    char* ldsW1a = lds + 65536;
    char* ldsW1b = lds + 98304;
    char* ldsH   = lds + 131072;
    float* ldsB1 = (float*)(lds + 147456);
    float* ldsB2 = (float*)(lds + 151552);
    int*  ldsPr  = (int*)(lds + 153600);

    // ---- bijective XCD swizzle (T1, m204): grid 1025 = 8*128 + 1.
    //      XCD k gets a CONTIGUOUS bid range -> <=2 branches' weights per
    //      XCD L2 (<=3MB of 4MB) even when blocks drift in phase.
    //      ob in [0,1025): xcd = ob&7, ii = ob>>3.
    //      xcd 0 -> bids [0,128] (129 blocks); xcd k>=1 -> [129+(k-1)*128, ...+127].
    const int ob = blockIdx.x;
    const int xcd = ob & 7, ii = ob >> 3;
    const int bid = (xcd == 0) ? ii : (129 + (xcd - 1) * 128 + ii);

    int branch, base, cnt;
    const int* perm;
    if (bid < 512) {
        branch = 2; base = bid * 128; cnt = NROWS; perm = nullptr;
    } else {
        int eb = bid - 512;
        int nb = offs[256];
        int nbb = (nb + 127) >> 7;
        int nc = NROWS - nb;
        int ncb = (nc + 127) >> 7;
        if (eb < nbb)            { branch = 0; base = eb * 128;         cnt = nb; perm = perm_b; }
        else if (eb < nbb + ncb) { branch = 1; base = (eb - nbb) * 128; cnt = nc; perm = perm_c; }
        else return;
    }

    const float* b1 = branch == 0 ? b1_0 : (branch == 1 ? b1_1 : b1_2);
    const float* b2 = branch == 0 ? b2_0 : (branch == 1 ? b2_1 : b2_2);
    const char* w1t = (const char*)(wts + (size_t)branch * (DH * DIN));
    const char* w2t = (const char*)(wts + (size_t)3 * DH * DIN + (size_t)branch * (DF * DH));

    const int t = threadIdx.x;
    const int lane = t & 63;
    const int w = t >> 6;
    const int l15 = lane & 15;
    const int g = lane >> 4;

    // ---- prologue: bias / perm-row tables into LDS (keeps the main loop's
    //      VMEM stream = exactly the 12 gll16s, so vmcnt counts are exact)
    ldsB1[t] = b1[t];
    ldsB1[t + 512] = b1[t + 512];
    ldsB2[t] = b2[t];
    if (t < 128) {
        int gr = base + t;
        ldsPr[t] = (gr < cnt) ? (perm ? perm[gr] : gr) : -1;
    }
    // ---- stage X [128][256] fp32->bf16, swizzled, into transient region
    #pragma unroll
    for (int i = 0; i < 16; ++i) {
        int idx = t + i * 512;            // 8192 float4 slots
        int r = idx >> 6, c4 = idx & 63;
        int gr = base + r;
        int grow = gr < cnt ? gr : cnt - 1;
        if (perm) grow = perm[grow];
        f32x4 v = *(const f32x4*)(obs + (size_t)grow * DIN + c4 * 4);
        ushort4 p4;
        p4.x = f2b(v.x); p4.y = f2b(v.y); p4.z = f2b(v.z); p4.w = f2b(v.w);
        *(ushort4*)(lds + r * 512 + ((c4 * 8) ^ ((r & 7) << 4))) = p4;
    }
    WAIT_LGKM();

    // ---- load persistent X A-frags (64 VGPR): wave rows rg*32..+32
    const int rg = w & 3, cg = w >> 2;   // GEMM1: 4 row-groups x 2 hcol-groups
    bf16x8 xf[2][8];
    #pragma unroll
    for (int art = 0; art < 2; ++art)
        #pragma unroll
        for (int kk = 0; kk < 8; ++kk) {
            int ar = rg * 32 + art * 16 + l15;
            xf[art][kk] = *(const bf16x8*)(lds + ar * 512 + ((kk * 64 + g * 16) ^ ((ar & 7) << 4)));
        }
    WAIT_LGKM();   // X region now dead -> becomes W2A/W2B

    // ---- issue chunk-0 prefetches: W1 first (4), then W2 halves (8)
    {
        #pragma unroll
        for (int i = 0; i < 4; ++i) {
            int slot = t + i * 512;
            int nl = slot >> 5, boff = (slot & 31) << 4;
            gll16(w1t + (size_t)nl * 512 + (boff ^ ((nl & 7) << 4)),
                  ldsW1a + slot * 16);
        }
        #pragma unroll
        for (int h = 0; h < 2; ++h) {
            char* dst = h ? ldsW2B : ldsW2A;
            #pragma unroll
            for (int i = 0; i < 4; ++i) {
                int slot = t + i * 512;
                int nl = slot >> 3, boff = (slot & 7) << 4;
                gll16(w2t + (size_t)(h * 256 + nl) * 2048 + (boff ^ ((nl & 7) << 4)),
                      dst + slot * 16);
            }
        }
    }

    const int wr = w >> 2, wc = w & 3;   // GEMM2: 2 row-groups x 4 fcol-groups
    f32x4 accA[4][4], accB[4][4];
    #pragma unroll
    for (int a = 0; a < 4; ++a)
        #pragma unroll
        for (int b = 0; b < 4; ++b)
            #pragma unroll
            for (int e = 0; e < 4; ++e) { accA[a][b][e] = 0.0f; accB[a][b][e] = 0.0f; }

    for (int hc = 0; hc < 16; ++hc) {
        WAIT_TOP();   // retires W1[hc] (oldest 4); W2[hc] (8) stays in flight
        const char* W1cur = (hc & 1) ? ldsW1b : ldsW1a;

        // ---- GEMM1: H chunk [128][64], K=256, wave tile 32x32, A from regs
        f32x4 aH[2][2];
        #pragma unroll
        for (int a = 0; a < 2; ++a)
            #pragma unroll
            for (int b = 0; b < 2; ++b)
                #pragma unroll
                for (int e = 0; e < 4; ++e) aH[a][b][e] = 0.0f;
        const int nl0 = cg * 32 + l15;
        const int nl1 = nl0 + 16;
        const int sw0 = (nl0 & 7) << 4, sw1 = (nl1 & 7) << 4;
        __builtin_amdgcn_s_setprio(1);
        #pragma unroll
        for (int kk = 0; kk < 8; ++kk) {
            int kb = kk * 64 + g * 16;
            bf16x8 bb0 = *(const bf16x8*)(W1cur + nl0 * 512 + (kb ^ sw0));
            bf16x8 bb1 = *(const bf16x8*)(W1cur + nl1 * 512 + (kb ^ sw1));
            aH[0][0] = __builtin_amdgcn_mfma_f32_16x16x32_bf16(xf[0][kk], bb0, aH[0][0], 0, 0, 0);
            aH[0][1] = __builtin_amdgcn_mfma_f32_16x16x32_bf16(xf[0][kk], bb1, aH[0][1], 0, 0, 0);
            aH[1][0] = __builtin_amdgcn_mfma_f32_16x16x32_bf16(xf[1][kk], bb0, aH[1][0], 0, 0, 0);
            aH[1][1] = __builtin_amdgcn_mfma_f32_16x16x32_bf16(xf[1][kk], bb1, aH[1][1], 0, 0, 0);
        }
        __builtin_amdgcn_s_setprio(0);

        // ---- bias + relu -> ldsH  (D: col=l15 -> hcol, row=g*4+r -> batch row)
        {
            float b1v0 = ldsB1[hc * 64 + cg * 32 + l15];
            float b1v1 = ldsB1[hc * 64 + cg * 32 + 16 + l15];
            #pragma unroll
            for (int art = 0; art < 2; ++art)
                #pragma unroll
                for (int bct = 0; bct < 2; ++bct) {
                    int col2 = (cg * 32 + bct * 16 + l15) * 2;
                    float bv = bct ? b1v1 : b1v0;
                    #pragma unroll
                    for (int r = 0; r < 4; ++r) {
                        int hrow = rg * 32 + art * 16 + g * 4 + r;
                        float vv = fmaxf(aH[art][bct][r] + bv, 0.0f);
                        *(unsigned short*)(ldsH + hrow * 128 + (col2 ^ ((hrow & 7) << 4))) = f2b(vv);
                    }
                }
        }

        // ---- issue W1[hc+1] into the other ping-pong buffer (hides under GEMM2)
        {
            char* dst = (hc & 1) ? ldsW1a : ldsW1b;
            int nchunk = (hc + 1) & 15;
            #pragma unroll
            for (int i = 0; i < 4; ++i) {
                int slot = t + i * 512;
                int nl = slot >> 5, boff = (slot & 31) << 4;
                gll16(w1t + (size_t)(nchunk * 64 + nl) * 512 + (boff ^ ((nl & 7) << 4)),
                      dst + slot * 16);
            }
        }

        WAIT_MID();   // retires W2[hc] (oldest 8); W1[hc+1] (4) stays in flight

        // ---- GEMM2 A-frags from H (reused across both halves)
        bf16x8 hA[4][2];
        #pragma unroll
        for (int rt = 0; rt < 4; ++rt)
            #pragma unroll
            for (int k2 = 0; k2 < 2; ++k2) {
                int hr = wr * 64 + rt * 16 + l15;
                hA[rt][k2] = *(const bf16x8*)(ldsH + hr * 128 + ((k2 * 64 + g * 16) ^ ((hr & 7) << 4)));
            }

        // ---- GEMM2: out[128][512] partial (k=64), wave tile 64x64 per half
        const int fc = wc * 64 + l15;   // +ct*16
        const int fsw0 = ((fc) & 7) << 4;
        __builtin_amdgcn_s_setprio(1);
        #pragma unroll
        for (int k2 = 0; k2 < 2; ++k2)
            #pragma unroll
            for (int ct = 0; ct < 4; ++ct) {
                int fr = fc + ct * 16;
                bf16x8 bb = *(const bf16x8*)(ldsW2A + fr * 128 + ((k2 * 64 + g * 16) ^ fsw0));
                #pragma unroll
                for (int rt = 0; rt < 4; ++rt)
                    accA[rt][ct] = __builtin_amdgcn_mfma_f32_16x16x32_bf16(hA[rt][k2], bb, accA[rt][ct], 0, 0, 0);
            }
        #pragma unroll
        for (int k2 = 0; k2 < 2; ++k2)
            #pragma unroll
            for (int ct = 0; ct < 4; ++ct) {
                int fr = fc + ct * 16;
                bf16x8 bb = *(const bf16x8*)(ldsW2B + fr * 128 + ((k2 * 64 + g * 16) ^ fsw0));
                #pragma unroll
                for (int rt = 0; rt < 4; ++rt)
                    accB[rt][ct] = __builtin_amdgcn_mfma_f32_16x16x32_bf16(hA[rt][k2], bb, accB[rt][ct], 0, 0, 0);
            }
        __builtin_amdgcn_s_setprio(0);

        WAIT_LGKM();  // all W2 reads done; W1[hc+1] still in flight

        // ---- issue W2[hc+1] halves (hide under next chunk's GEMM1)
        {
            int nchunk = (hc + 1) & 15;
            #pragma unroll
            for (int h = 0; h < 2; ++h) {
                char* dst = h ? ldsW2B : ldsW2A;
                #pragma unroll
                for (int i = 0; i < 4; ++i) {
                    int slot = t + i * 512;
                    int nl = slot >> 3, boff = (slot & 7) << 4;
                    gll16(w2t + (size_t)(h * 256 + nl) * 2048 + nchunk * 128 + (boff ^ ((nl & 7) << 4)),
                          dst + slot * 16);
                }
            }
        }
    }

    // ---- epilogue: bias2 + permuted scatter store
    int colq[8]; float b2v[8];
    #pragma unroll
    for (int q = 0; q < 8; ++q) {
        colq[q] = (q >> 2) * 256 + wc * 64 + (q & 3) * 16 + l15;
        b2v[q] = ldsB2[colq[q]];
    }
    const int cb = (branch == 2) ? DF : 0;
    #pragma unroll
    for (int rt = 0; rt < 4; ++rt)
        #pragma unroll
        for (int r = 0; r < 4; ++r) {
            int row = wr * 64 + rt * 16 + g * 4 + r;
            int prow = ldsPr[row];
            if (prow >= 0) {
                float* op = out + (size_t)prow * (2 * DF) + cb;
                op[colq[0]] = accA[rt][0][r] + b2v[0];
                op[colq[1]] = accA[rt][1][r] + b2v[1];
                op[colq[2]] = accA[rt][2][r] + b2v[2];
                op[colq[3]] = accA[rt][3][r] + b2v[3];
                op[colq[4]] = accB[rt][0][r] + b2v[4];
                op[colq[5]] = accB[rt][1][r] + b2v[5];
                op[colq[6]] = accB[rt][2][r] + b2v[6];
                op[colq[7]] = accB[rt][3][r] + b2v[7];
            }
        }
}

extern "C" void kernel_launch(void* const* d_in, const int* in_sizes, int n_in,
                              void* d_out, int out_size, void* d_ws, size_t ws_size,
                              hipStream_t stream) {
    const float* obs = (const float*)d_in[0];
    const float* W1[3] = {(const float*)d_in[1], (const float*)d_in[5], (const float*)d_in[9]};
    const float* b1[3] = {(const float*)d_in[2], (const float*)d_in[6], (const float*)d_in[10]};
    const float* W2[3] = {(const float*)d_in[3], (const float*)d_in[7], (const float*)d_in[11]};
    const float* b2[3] = {(const float*)d_in[4], (const float*)d_in[8], (const float*)d_in[12]};

    char* ws = (char*)d_ws;
    unsigned short* wts = (unsigned short*)(ws + WS_WTS);
    int* pb   = (int*)(ws + WS_PB);
    int* pc   = (int*)(ws + WS_PC);
    int* cnt  = (int*)(ws + WS_CNT);
    int* offs = (int*)(ws + WS_OFFS);

    for (int br = 0; br < 3; ++br) {
        transpose_to_bf16<<<dim3(DIN / 64, DH / 64), 256, 0, stream>>>(
            W1[br], wts + (size_t)br * DH * DIN, DIN, DH);
        transpose_to_bf16<<<dim3(DH / 64, DF / 64), 256, 0, stream>>>(
            W2[br], wts + (size_t)3 * DH * DIN + (size_t)br * DF * DH, DH, DF);
    }
    tag_count<<<256, 256, 0, stream>>>(obs, cnt);
    scan256<<<1, 256, 0, stream>>>(cnt, offs);
    fill_perm<<<256, 256, 0, stream>>>(obs, offs, pb, pc);

    hipFuncSetAttribute((const void*)fused_mlp,
                        hipFuncAttributeMaxDynamicSharedMemorySize, 154112);
    fused_mlp<<<1025, 512, 154112, stream>>>(obs, wts, pb, pc, offs,
        b1[0], b2[0], b1[1], b2[1], b1[2], b2[2], (float*)d_out);
}

// Round 6
// 376.205 us; speedup vs baseline: 2.0607x; 2.0006x over previous
//
#include <hip/hip_runtime.h>
#include <hip/hip_bf16.h>

#define DIN 256
#define DH  1024
#define DF  512
#define NROWS 65536

// workspace layout (bytes)
#define WS_WTS   0
#define WS_PB    4718592
#define WS_PC    4980736
#define WS_CNT   5242880
#define WS_OFFS  5243904

typedef __attribute__((ext_vector_type(8))) short bf16x8;
typedef __attribute__((ext_vector_type(4))) float f32x4;

__device__ __forceinline__ unsigned short f2b(float f) {
    union { float f; unsigned u; } v; v.f = f;
    unsigned r = v.u + 0x7FFFu + ((v.u >> 16) & 1u);
    return (unsigned short)(r >> 16);
}

__device__ __forceinline__ void gll16(const void* g, void* l) {
    __builtin_amdgcn_global_load_lds(
        (const __attribute__((address_space(1))) void*)g,
        (__attribute__((address_space(3))) void*)l, 16, 0, 0);
}

// dst[n][k] = (bf16) src[k][n] ; src is K x N row-major fp32
__global__ __launch_bounds__(256) void transpose_to_bf16(
        const float* __restrict__ src, unsigned short* __restrict__ dst,
        int K, int N) {
    __shared__ float tile[64][65];
    int k0 = blockIdx.x * 64, n0 = blockIdx.y * 64;
    int t = threadIdx.x;
    for (int i = 0; i < 16; ++i) {
        int idx = t + i * 256;
        int kk = idx >> 6, nn = idx & 63;
        tile[kk][nn] = src[(size_t)(k0 + kk) * N + (n0 + nn)];
    }
    __syncthreads();
    for (int i = 0; i < 16; ++i) {
        int idx = t + i * 256;
        int nn = idx >> 6, kk = idx & 63;
        dst[(size_t)(n0 + nn) * K + (k0 + kk)] = f2b(tile[kk][nn]);
    }
}

__device__ __forceinline__ int row_tag(const float* obs, int row) {
    float c2 = obs[(size_t)row * DIN + 2];
    float c3 = obs[(size_t)row * DIN + 3];
    return (c2 == 1.0f && c3 == 0.0f) ? 1 : 0;
}

__global__ __launch_bounds__(256) void tag_count(const float* __restrict__ obs,
                                                 int* __restrict__ cnt) {
    int t = threadIdx.x;
    int tag = row_tag(obs, blockIdx.x * 256 + t);
    unsigned long long m = __ballot(tag);
    __shared__ int wc[4];
    if ((t & 63) == 0) wc[t >> 6] = __popcll(m);
    __syncthreads();
    if (t == 0) cnt[blockIdx.x] = wc[0] + wc[1] + wc[2] + wc[3];
}

__global__ __launch_bounds__(256) void scan256(const int* __restrict__ cnt,
                                               int* __restrict__ offs) {
    __shared__ int s[256];
    int t = threadIdx.x;
    s[t] = cnt[t];
    __syncthreads();
    for (int d = 1; d < 256; d <<= 1) {
        int v = (t >= d) ? s[t - d] : 0;
        __syncthreads();
        s[t] += v;
        __syncthreads();
    }
    offs[t] = s[t] - cnt[t];
    if (t == 255) offs[256] = s[255];
}

__global__ __launch_bounds__(256) void fill_perm(const float* __restrict__ obs,
                                                 const int* __restrict__ offs,
                                                 int* __restrict__ pb,
                                                 int* __restrict__ pc) {
    int t = threadIdx.x, bid = blockIdx.x;
    int row = bid * 256 + t;
    int tag = row_tag(obs, row);
    unsigned long long m = __ballot(tag);
    __shared__ int wc[4];
    int lane = t & 63, wv = t >> 6;
    if (lane == 0) wc[wv] = __popcll(m);
    __syncthreads();
    int woff = 0;
    for (int i = 0; i < 4; ++i) if (i < wv) woff += wc[i];
    int lb = woff + __popcll(m & ((1ull << lane) - 1ull));
    int base_b = offs[bid];
    if (tag) pb[base_b + lb] = row;
    else     pc[bid * 256 - base_b + (t - lb)] = row;
}

// LDS map (dynamic, 154112 B, 1 block/CU). ALL barriers are __syncthreads
// (full drains — the proven-clean R1 mechanism). Every stage burst is issued
// at the START of a compute interval so its latency hides under 16-32 MFMA.
//   ldsX   @ 0      [128][256] bf16 = 64K  persistent, swz (r&7)<<4
//   ldsW1  @ 65536  [64][256]  bf16 = 32K  single-buffered W1 chunk
//   ldsQA  @ 98304  [128][64]  bf16 = 16K  W2 quarter ping
//   ldsQB  @ 114688 [128][64]  bf16 = 16K  W2 quarter pong
//   ldsH   @ 131072 [128][64]  bf16 = 16K
//   ldsB1  @ 147456 float[1024]
//   ldsB2  @ 151552 float[512]
//   ldsPr  @ 153600 int[128]
__global__ __launch_bounds__(512, 2) void fused_mlp(
    const float* __restrict__ obs,
    const unsigned short* __restrict__ wts,
    const int* __restrict__ perm_b, const int* __restrict__ perm_c,
    const int* __restrict__ offs,
    const float* __restrict__ b1_0, const float* __restrict__ b2_0,
    const float* __restrict__ b1_1, const float* __restrict__ b2_1,
    const float* __restrict__ b1_2, const float* __restrict__ b2_2,
    float* __restrict__ out)
{
    extern __shared__ char lds[];
    char* ldsX  = lds;
    char* ldsW1 = lds + 65536;
    char* ldsQA = lds + 98304;
    char* ldsQB = lds + 114688;
    char* ldsH  = lds + 131072;
    float* ldsB1 = (float*)(lds + 147456);
    float* ldsB2 = (float*)(lds + 151552);
    int*  ldsPr  = (int*)(lds + 153600);

    // bijective XCD swizzle: contiguous bid range per XCD
    const int ob = blockIdx.x;
    const int xcd = ob & 7, ii = ob >> 3;
    const int bid = (xcd == 0) ? ii : (129 + (xcd - 1) * 128 + ii);

    int branch, base, cnt;
    const int* perm;
    if (bid < 512) {
        branch = 2; base = bid * 128; cnt = NROWS; perm = nullptr;
    } else {
        int eb = bid - 512;
        int nb = offs[256];
        int nbb = (nb + 127) >> 7;
        int nc = NROWS - nb;
        int ncb = (nc + 127) >> 7;
        if (eb < nbb)            { branch = 0; base = eb * 128;         cnt = nb; perm = perm_b; }
        else if (eb < nbb + ncb) { branch = 1; base = (eb - nbb) * 128; cnt = nc; perm = perm_c; }
        else return;
    }

    const float* b1 = branch == 0 ? b1_0 : (branch == 1 ? b1_1 : b1_2);
    const float* b2 = branch == 0 ? b2_0 : (branch == 1 ? b2_1 : b2_2);
    const char* w1t = (const char*)(wts + (size_t)branch * (DH * DIN));
    const char* w2t = (const char*)(wts + (size_t)3 * DH * DIN + (size_t)branch * (DF * DH));

    const int t = threadIdx.x;
    const int lane = t & 63;
    const int w = t >> 6;
    const int l15 = lane & 15;
    const int g = lane >> 4;

    // ---- prologue: tables + X staging
    ldsB1[t] = b1[t];
    ldsB1[t + 512] = b1[t + 512];
    ldsB2[t] = b2[t];
    if (t < 128) {
        int gr = base + t;
        ldsPr[t] = (gr < cnt) ? (perm ? perm[gr] : gr) : -1;
    }
    #pragma unroll
    for (int i = 0; i < 16; ++i) {
        int idx = t + i * 512;
        int r = idx >> 6, c4 = idx & 63;
        int gr = base + r;
        int grow = gr < cnt ? gr : cnt - 1;
        if (perm) grow = perm[grow];
        f32x4 v = *(const f32x4*)(obs + (size_t)grow * DIN + c4 * 4);
        ushort4 p4;
        p4.x = f2b(v.x); p4.y = f2b(v.y); p4.z = f2b(v.z); p4.w = f2b(v.w);
        *(ushort4*)(ldsX + r * 512 + ((c4 * 8) ^ ((r & 7) << 4))) = p4;
    }
    // stage W1[0] (only exposed stage; once per block)
    #pragma unroll
    for (int i = 0; i < 4; ++i) {
        int slot = t + i * 512;
        int nl = slot >> 5, boff = (slot & 31) << 4;
        gll16(w1t + (size_t)nl * 512 + (boff ^ ((nl & 7) << 4)), ldsW1 + slot * 16);
    }
    __syncthreads();

    // wave roles
    const int rg = w & 3, cg = w >> 2;   // GEMM1: rows rg*32, hcols cg*32
    const int wr = w >> 2, wc = w & 3;   // GEMM2: rows wr*64, fcols wc*32/quarter

    const int ar0 = rg * 32 + l15, ar1 = ar0 + 16;
    const int asw0 = (ar0 & 7) << 4, asw1 = (ar1 & 7) << 4;
    const int bn0 = cg * 32 + l15, bn1 = bn0 + 16;
    const int bsw0 = (bn0 & 7) << 4, bsw1 = (bn1 & 7) << 4;

    f32x4 acc[4][8];
    #pragma unroll
    for (int a = 0; a < 4; ++a)
        #pragma unroll
        for (int b = 0; b < 8; ++b)
            #pragma unroll
            for (int e = 0; e < 4; ++e) acc[a][b][e] = 0.0f;

    // W2 quarter stage helper: quarter q of chunk hc -> buf (2 gll16/thread)
    #define STAGE_Q(buf, q, hc_)                                               \
        {                                                                      \
            _Pragma("unroll")                                                  \
            for (int i = 0; i < 2; ++i) {                                      \
                int slot = t + i * 512;                                        \
                int nl = slot >> 3, boff = (slot & 7) << 4;                    \
                gll16(w2t + (size_t)((q) * 128 + nl) * 2048 + (hc_) * 128      \
                          + (boff ^ ((nl & 7) << 4)),                          \
                      (buf) + slot * 16);                                      \
            }                                                                  \
        }

    #define QUARTER_MFMA(buf, c0)                                              \
        {                                                                      \
            _Pragma("unroll")                                                  \
            for (int k2 = 0; k2 < 2; ++k2)                                     \
                _Pragma("unroll")                                              \
                for (int ct = 0; ct < 2; ++ct) {                               \
                    int fr = wc * 32 + ct * 16 + l15;                          \
                    bf16x8 bb = *(const bf16x8*)((buf) + fr * 128 +            \
                                 ((k2 * 64 + g * 16) ^ ((fr & 7) << 4)));      \
                    _Pragma("unroll")                                          \
                    for (int rt = 0; rt < 4; ++rt)                             \
                        acc[rt][(c0) + ct] = __builtin_amdgcn_mfma_f32_16x16x32_bf16( \
                            hA[rt][k2], bb, acc[rt][(c0) + ct], 0, 0, 0);      \
                }                                                              \
        }

    for (int hc = 0; hc < 16; ++hc) {
        // ---- I1: stage q0->QA ; GEMM1 + bias/relu -> H
        STAGE_Q(ldsQA, 0, hc);
        f32x4 aH[2][2];
        #pragma unroll
        for (int a = 0; a < 2; ++a)
            #pragma unroll
            for (int b = 0; b < 2; ++b)
                #pragma unroll
                for (int e = 0; e < 4; ++e) aH[a][b][e] = 0.0f;
        __builtin_amdgcn_s_setprio(1);
        #pragma unroll
        for (int kk = 0; kk < 8; ++kk) {
            int kb = kk * 64 + g * 16;
            bf16x8 a0 = *(const bf16x8*)(ldsX  + ar0 * 512 + (kb ^ asw0));
            bf16x8 a1 = *(const bf16x8*)(ldsX  + ar1 * 512 + (kb ^ asw1));
            bf16x8 b0 = *(const bf16x8*)(ldsW1 + bn0 * 512 + (kb ^ bsw0));
            bf16x8 b1f = *(const bf16x8*)(ldsW1 + bn1 * 512 + (kb ^ bsw1));
            aH[0][0] = __builtin_amdgcn_mfma_f32_16x16x32_bf16(a0, b0,  aH[0][0], 0, 0, 0);
            aH[0][1] = __builtin_amdgcn_mfma_f32_16x16x32_bf16(a0, b1f, aH[0][1], 0, 0, 0);
            aH[1][0] = __builtin_amdgcn_mfma_f32_16x16x32_bf16(a1, b0,  aH[1][0], 0, 0, 0);
            aH[1][1] = __builtin_amdgcn_mfma_f32_16x16x32_bf16(a1, b1f, aH[1][1], 0, 0, 0);
        }
        __builtin_amdgcn_s_setprio(0);
        {
            float b1v0 = ldsB1[hc * 64 + cg * 32 + l15];
            float b1v1 = ldsB1[hc * 64 + cg * 32 + 16 + l15];
            #pragma unroll
            for (int art = 0; art < 2; ++art)
                #pragma unroll
                for (int bct = 0; bct < 2; ++bct) {
                    int col2 = (cg * 32 + bct * 16 + l15) * 2;
                    float bv = bct ? b1v1 : b1v0;
                    #pragma unroll
                    for (int r = 0; r < 4; ++r) {
                        int hrow = rg * 32 + art * 16 + g * 4 + r;
                        float vv = fmaxf(aH[art][bct][r] + bv, 0.0f);
                        *(unsigned short*)(ldsH + hrow * 128 + (col2 ^ ((hrow & 7) << 4))) = f2b(vv);
                    }
                }
        }
        __syncthreads();   // B1: drains q0; H visible

        // ---- I2: stage q1->QB ; hA loads ; GEMM2 q0 (QA)
        STAGE_Q(ldsQB, 1, hc);
        bf16x8 hA[4][2];
        #pragma unroll
        for (int rt = 0; rt < 4; ++rt)
            #pragma unroll
            for (int k2 = 0; k2 < 2; ++k2) {
                int hr = wr * 64 + rt * 16 + l15;
                hA[rt][k2] = *(const bf16x8*)(ldsH + hr * 128 + ((k2 * 64 + g * 16) ^ ((hr & 7) << 4)));
            }
        __builtin_amdgcn_s_setprio(1);
        QUARTER_MFMA(ldsQA, 0);
        __builtin_amdgcn_s_setprio(0);
        __syncthreads();   // B2: drains q1

        // ---- I3: stage q2->QA ; GEMM2 q1 (QB)
        STAGE_Q(ldsQA, 2, hc);
        __builtin_amdgcn_s_setprio(1);
        QUARTER_MFMA(ldsQB, 2);
        __builtin_amdgcn_s_setprio(0);
        __syncthreads();   // B3: drains q2

        // ---- I4: stage q3->QB ; GEMM2 q2 (QA)
        STAGE_Q(ldsQB, 3, hc);
        __builtin_amdgcn_s_setprio(1);
        QUARTER_MFMA(ldsQA, 4);
        __builtin_amdgcn_s_setprio(0);
        __syncthreads();   // B4: drains q3

        // ---- I5: stage W1[hc+1] ; GEMM2 q3 (QB)
        if (hc < 15) {
            int nchunk = hc + 1;
            #pragma unroll
            for (int i = 0; i < 4; ++i) {
                int slot = t + i * 512;
                int nl = slot >> 5, boff = (slot & 31) << 4;
                gll16(w1t + (size_t)(nchunk * 64 + nl) * 512 + (boff ^ ((nl & 7) << 4)),
                      ldsW1 + slot * 16);
            }
        }
        __builtin_amdgcn_s_setprio(1);
        QUARTER_MFMA(ldsQB, 6);
        __builtin_amdgcn_s_setprio(0);
        __syncthreads();   // B5: drains W1[hc+1]
    }

    // ---- epilogue: bias2 + permuted scatter store
    int colq[8]; float b2v[8];
    #pragma unroll
    for (int q = 0; q < 8; ++q) {
        colq[q] = (q >> 1) * 128 + wc * 32 + (q & 1) * 16 + l15;
        b2v[q] = ldsB2[colq[q]];
    }
    const int cb = (branch == 2) ? DF : 0;
    #pragma unroll
    for (int rt = 0; rt < 4; ++rt)
        #pragma unroll
        for (int r = 0; r < 4; ++r) {
            int row = wr * 64 + rt * 16 + g * 4 + r;
            int prow = ldsPr[row];
            if (prow >= 0) {
                float* op = out + (size_t)prow * (2 * DF) + cb;
                #pragma unroll
                for (int q = 0; q < 8; ++q)
                    op[colq[q]] = acc[rt][q][r] + b2v[q];
            }
        }
}

extern "C" void kernel_launch(void* const* d_in, const int* in_sizes, int n_in,
                              void* d_out, int out_size, void* d_ws, size_t ws_size,
                              hipStream_t stream) {
    const float* obs = (const float*)d_in[0];
    const float* W1[3] = {(const float*)d_in[1], (const float*)d_in[5], (const float*)d_in[9]};
    const float* b1[3] = {(const float*)d_in[2], (const float*)d_in[6], (const float*)d_in[10]};
    const float* W2[3] = {(const float*)d_in[3], (const float*)d_in[7], (const float*)d_in[11]};
    const float* b2[3] = {(const float*)d_in[4], (const float*)d_in[8], (const float*)d_in[12]};

    char* ws = (char*)d_ws;
    unsigned short* wts = (unsigned short*)(ws + WS_WTS);
    int* pb   = (int*)(ws + WS_PB);
    int* pc   = (int*)(ws + WS_PC);
    int* cnt  = (int*)(ws + WS_CNT);
    int* offs = (int*)(ws + WS_OFFS);

    for (int br = 0; br < 3; ++br) {
        transpose_to_bf16<<<dim3(DIN / 64, DH / 64), 256, 0, stream>>>(
            W1[br], wts + (size_t)br * DH * DIN, DIN, DH);
        transpose_to_bf16<<<dim3(DH / 64, DF / 64), 256, 0, stream>>>(
            W2[br], wts + (size_t)3 * DH * DIN + (size_t)br * DF * DH, DH, DF);
    }
    tag_count<<<256, 256, 0, stream>>>(obs, cnt);
    scan256<<<1, 256, 0, stream>>>(cnt, offs);
    fill_perm<<<256, 256, 0, stream>>>(obs, offs, pb, pc);

    hipFuncSetAttribute((const void*)fused_mlp,
                        hipFuncAttributeMaxDynamicSharedMemorySize, 154112);
    fused_mlp<<<1025, 512, 154112, stream>>>(obs, wts, pb, pc, offs,
        b1[0], b2[0], b1[1], b2[1], b1[2], b2[2], (float*)d_out);
}